// Round 10
// baseline (431.712 us; speedup 1.0000x reference)
//
#include <hip/hip_runtime.h>
#include <math.h>

#define TAU_INV 1.25f
#define LAMBDA 0.5f
#define NR 4096
#define HD 512

typedef __attribute__((ext_vector_type(8))) short short8;
typedef __attribute__((ext_vector_type(4))) float f32x4;
typedef __attribute__((ext_vector_type(4))) unsigned short ushort4v;

static __device__ __forceinline__ unsigned short f2bf(float f) {
  unsigned int u = __float_as_uint(f);
  u += 0x7fff + ((u >> 16) & 1);   // RNE
  return (unsigned short)(u >> 16);
}
static __device__ __forceinline__ float bf2f(unsigned short s) {
  return __uint_as_float(((unsigned int)s) << 16);
}

// ---------------- fp32 -> bf16 cast (vectorized) ----------------
__global__ __launch_bounds__(256) void cast_bf16(const float* __restrict__ src,
                                                 unsigned short* __restrict__ dst, int n4) {
  int i = blockIdx.x * 256 + threadIdx.x;
  if (i < n4) {
    float4 v = ((const float4*)src)[i];
    ushort4v o;
    o.x = f2bf(v.x); o.y = f2bf(v.y); o.z = f2bf(v.z); o.w = f2bf(v.w);
    ((ushort4v*)dst)[i] = o;
  }
}

// ---------------- zsumb = bf16(a + b) (for pair loss) ----------------
__global__ __launch_bounds__(256) void addz_bf(const float* __restrict__ a,
                                               const float* __restrict__ b,
                                               unsigned short* __restrict__ o, int n4) {
  int i = blockIdx.x * 256 + threadIdx.x;
  if (i < n4) {
    float4 x = ((const float4*)a)[i], y = ((const float4*)b)[i];
    ushort4v r;
    r.x = f2bf(x.x + y.x); r.y = f2bf(x.y + y.y);
    r.z = f2bf(x.z + y.z); r.w = f2bf(x.w + y.w);
    ((ushort4v*)o)[i] = r;
  }
}

// ---------------- pos -> bitmask (1 bit per element, wave-ballot) ----------------
__global__ __launch_bounds__(256) void pos_pack(const float* __restrict__ pos,
                                                unsigned long long* __restrict__ bits) {
  int lane = threadIdx.x & 63;
  int gw = (blockIdx.x * 256 + threadIdx.x) >> 6;
  int stride = (gridDim.x * 256) >> 6;
  const int nwords = NR * NR / 64;
  for (int w = gw; w < nwords; w += stride) {
    float v = pos[(size_t)w * 64 + lane];
    unsigned long long m = __ballot(v > 0.5f);
    if (lane == 0) bits[w] = m;
  }
}

// ============ MFMA GEMM core macros (128x128 tile, BK=64, XOR-swizzled LDS) ============
// LDS slot (row, c16) holds global element (row, c16 ^ ((row&7)<<4)); reads re-apply the XOR.

#define GEMM_STAGE(Aptr, Bptr, rb, cb_, kb)                                                     \
  {                                                                                             \
    _Pragma("unroll") for (int q = 0; q < 4; ++q) {                                             \
      int r0 = q * 32 + w * 8;                                                                  \
      const char* sa = (const char*)(Aptr) + ((size_t)((rb) + r0 + lrow) << 10) + (kb)*128 + scb;\
      const char* sb = (const char*)(Bptr) + ((size_t)((cb_) + r0 + lrow) << 10) + (kb)*128 + scb;\
      __builtin_amdgcn_global_load_lds((const __attribute__((address_space(1))) unsigned int*)sa,\
          (__attribute__((address_space(3))) unsigned int*)(void*)((char*)As + r0 * 128), 16, 0, 0);\
      __builtin_amdgcn_global_load_lds((const __attribute__((address_space(1))) unsigned int*)sb,\
          (__attribute__((address_space(3))) unsigned int*)(void*)((char*)Bs + r0 * 128), 16, 0, 0);\
    }                                                                                           \
  }

#define GEMM_COMPUTE()                                                                          \
  {                                                                                             \
    _Pragma("unroll") for (int kk = 0; kk < 2; ++kk) {                                          \
      short8 av[4], bv[4];                                                                      \
      _Pragma("unroll") for (int mf = 0; mf < 4; ++mf) {                                        \
        int row = wr * 64 + mf * 16 + (l & 15);                                                 \
        int kbyte = ((kk * 64) + ((l >> 4) * 16)) ^ ((l & 7) << 4);                             \
        av[mf] = *(const short8*)((const char*)As + row * 128 + kbyte);                         \
      }                                                                                        \
      _Pragma("unroll") for (int nf = 0; nf < 4; ++nf) {                                        \
        int row = wc * 64 + nf * 16 + (l & 15);                                                 \
        int kbyte = ((kk * 64) + ((l >> 4) * 16)) ^ ((l & 7) << 4);                             \
        bv[nf] = *(const short8*)((const char*)Bs + row * 128 + kbyte);                         \
      }                                                                                        \
      _Pragma("unroll") for (int mf = 0; mf < 4; ++mf)                                          \
        _Pragma("unroll") for (int nf = 0; nf < 4; ++nf)                                        \
          acc[mf][nf] = __builtin_amdgcn_mfma_f32_16x16x32_bf16(av[mf], bv[nf], acc[mf][nf], 0, 0, 0);\
    }                                                                                           \
  }

// ---------------- proj GEMM: C = A @ W^T + bias (optional ELU), bf16 in/out, 2 streams ----------------
template <bool DO_ELU>
__global__ __launch_bounds__(256) void proj_mfma(const unsigned short* __restrict__ A0,
                                                 const unsigned short* __restrict__ A1,
                                                 const unsigned short* __restrict__ B,
                                                 const float* __restrict__ bias,
                                                 unsigned short* __restrict__ C0,
                                                 unsigned short* __restrict__ C1) {
  __shared__ unsigned short As[128 * 64];
  __shared__ unsigned short Bs[128 * 64];
  const int tid = threadIdx.x;
  const int l = tid & 63, w = tid >> 6;
  const int wr = w >> 1, wc = w & 1;
  const int stream_id = blockIdx.y >> 5;
  const int rowbase = (blockIdx.y & 31) * 128;
  const int colbase = blockIdx.x * 128;
  const unsigned short* A = stream_id ? A1 : A0;
  unsigned short* C = stream_id ? C1 : C0;
  const int lrow = l >> 3;
  const int scb = ((l & 7) ^ lrow) << 4;

  f32x4 acc[4][4];
#pragma unroll
  for (int i = 0; i < 4; ++i)
#pragma unroll
    for (int j = 0; j < 4; ++j) acc[i][j] = (f32x4){0.f, 0.f, 0.f, 0.f};

  for (int kb = 0; kb < 8; ++kb) {
    GEMM_STAGE(A, B, rowbase, colbase, kb);
    __syncthreads();
    GEMM_COMPUTE();
    __syncthreads();
  }

  const int cq = l >> 4, cn = l & 15;
#pragma unroll
  for (int mf = 0; mf < 4; ++mf) {
#pragma unroll
    for (int nf = 0; nf < 4; ++nf) {
      int col = colbase + wc * 64 + nf * 16 + cn;
      float bb = bias[col];
#pragma unroll
      for (int j = 0; j < 4; ++j) {
        int row = rowbase + wr * 64 + mf * 16 + cq * 4 + j;
        float v = acc[mf][nf][j] + bb;
        if (DO_ELU) v = v > 0.f ? v : expm1f(v);
        C[(size_t)row * HD + col] = f2bf(v);
      }
    }
  }
}

// ---------------- row inv-norms from bf16 [rows,512] ----------------
__global__ __launch_bounds__(256) void rownorm_bf(const unsigned short* __restrict__ Z,
                                                  float* __restrict__ inv, int rows) {
  int wid = blockIdx.x * 4 + (threadIdx.x >> 6);
  int lane = threadIdx.x & 63;
  if (wid >= rows) return;
  short8 v = ((const short8*)(Z + (size_t)wid * HD))[lane];
  float s = 0.f;
#pragma unroll
  for (int j = 0; j < 8; ++j) {
    float f = bf2f((unsigned short)v[j]);
    s += f * f;
  }
#pragma unroll
  for (int off = 1; off < 64; off <<= 1) s += __shfl_xor(s, off);
  if (lane == 0) inv[wid] = 1.f / sqrtf(s);
}

// ---------------- fused similarity (MFMA) + exp + bitmask pos row/col reductions ----------------
__global__ __launch_bounds__(256) void sim_mfma(const unsigned short* __restrict__ PA,
                                                const unsigned short* __restrict__ PB,
                                                const float* __restrict__ invA,
                                                const float* __restrict__ invB,
                                                const unsigned int* __restrict__ BM,  // bitmask, row*128 u32s
                                                float* __restrict__ accRS,
                                                float* __restrict__ accRP,
                                                float* __restrict__ accCS,
                                                float* __restrict__ accCP) {
  __shared__ unsigned short As[128 * 64];
  __shared__ unsigned short Bs[128 * 64];
  const int tid = threadIdx.x;
  const int l = tid & 63, w = tid >> 6;
  const int wr = w >> 1, wc = w & 1;
  const int rowbase = blockIdx.y * 128;
  const int colbase = blockIdx.x * 128;
  const int lrow = l >> 3;
  const int scb = ((l & 7) ^ lrow) << 4;

  f32x4 acc[4][4];
#pragma unroll
  for (int i = 0; i < 4; ++i)
#pragma unroll
    for (int j = 0; j < 4; ++j) acc[i][j] = (f32x4){0.f, 0.f, 0.f, 0.f};

  for (int kb = 0; kb < 8; ++kb) {
    GEMM_STAGE(PA, PB, rowbase, colbase, kb);
    __syncthreads();
    GEMM_COMPUTE();
    __syncthreads();
  }

  const int cq = l >> 4, cn = l & 15;
  // scales
  float sr[4][4], sc[4];
#pragma unroll
  for (int mf = 0; mf < 4; ++mf) {
    float4 iv = *(const float4*)(invA + rowbase + wr * 64 + mf * 16 + cq * 4);
    sr[mf][0] = iv.x * TAU_INV; sr[mf][1] = iv.y * TAU_INV;
    sr[mf][2] = iv.z * TAU_INV; sr[mf][3] = iv.w * TAU_INV;
  }
#pragma unroll
  for (int nf = 0; nf < 4; ++nf) sc[nf] = invB[colbase + wc * 64 + nf * 16 + cn];

  // m = exp(dot * invA * invB / tau), in place
#pragma unroll
  for (int mf = 0; mf < 4; ++mf)
#pragma unroll
    for (int nf = 0; nf < 4; ++nf)
#pragma unroll
      for (int j = 0; j < 4; ++j)
        acc[mf][nf][j] = expf(acc[mf][nf][j] * sr[mf][j] * sc[nf]);

  // row sums + pos-weighted row sums (pos bits from BM[row][col])
#pragma unroll
  for (int mf = 0; mf < 4; ++mf) {
    float rs[4] = {0.f, 0.f, 0.f, 0.f}, rp[4] = {0.f, 0.f, 0.f, 0.f};
#pragma unroll
    for (int j = 0; j < 4; ++j) {
      int row = rowbase + wr * 64 + mf * 16 + cq * 4 + j;
      const unsigned int* bmr = BM + (size_t)row * 128 + (colbase >> 5) + wc * 2;
      unsigned int w0 = bmr[0], w1 = bmr[1];   // cols [base,base+32), [base+32,base+64)
#pragma unroll
      for (int nf = 0; nf < 4; ++nf) {
        float m = acc[mf][nf][j];
        rs[j] += m;
        unsigned int wsel = (nf < 2) ? w0 : w1;
        if ((wsel >> ((nf * 16 + cn) & 31)) & 1) rp[j] += m;
      }
    }
#pragma unroll
    for (int off = 1; off < 16; off <<= 1) {
#pragma unroll
      for (int j = 0; j < 4; ++j) { rs[j] += __shfl_xor(rs[j], off); rp[j] += __shfl_xor(rp[j], off); }
    }
    if (cn == 0) {
#pragma unroll
      for (int j = 0; j < 4; ++j) {
        int row = rowbase + wr * 64 + mf * 16 + cq * 4 + j;
        atomicAdd(&accRS[row], rs[j]);
        atomicAdd(&accRP[row], rp[j]);
      }
    }
  }

  // col sums + pos^T-weighted col sums (pos bits from BM[col][row])
  float cs[4] = {0.f, 0.f, 0.f, 0.f}, cp[4] = {0.f, 0.f, 0.f, 0.f};
#pragma unroll
  for (int nf = 0; nf < 4; ++nf) {
    int col = colbase + wc * 64 + nf * 16 + cn;
    const unsigned int* bmc = BM + (size_t)col * 128 + (rowbase >> 5) + wr * 2;
    unsigned int w0 = bmc[0], w1 = bmc[1];     // rows [base,base+32), [base+32,base+64)
#pragma unroll
    for (int mf = 0; mf < 4; ++mf) {
      unsigned int wsel = (mf < 2) ? w0 : w1;
#pragma unroll
      for (int j = 0; j < 4; ++j) {
        float m = acc[mf][nf][j];
        cs[nf] += m;
        if ((wsel >> ((mf * 16 + cq * 4 + j) & 31)) & 1) cp[nf] += m;
      }
    }
  }
#pragma unroll
  for (int off = 16; off < 64; off <<= 1) {
#pragma unroll
    for (int nf = 0; nf < 4; ++nf) { cs[nf] += __shfl_xor(cs[nf], off); cp[nf] += __shfl_xor(cp[nf], off); }
  }
  if (cq == 0) {
#pragma unroll
    for (int nf = 0; nf < 4; ++nf) {
      int col = colbase + wc * 64 + nf * 16 + cn;
      atomicAdd(&accCS[col], cs[nf]);
      atomicAdd(&accCP[col], cp[nf]);
    }
  }
}

// ---------------- pair dot + log-sigmoid (bf16 zsum gathers) ----------------
__global__ __launch_bounds__(256) void pair_logsig(const unsigned short* __restrict__ ZS1,
                                                   const unsigned short* __restrict__ ZS2,
                                                   const int* __restrict__ pi,
                                                   const int* __restrict__ pj,
                                                   const int* __restrict__ ni,
                                                   const int* __restrict__ nj,
                                                   int P, float* __restrict__ lsig) {
  int wid = blockIdx.x * 4 + (threadIdx.x >> 6);
  int lane = threadIdx.x & 63;
  if (wid >= 2 * P) return;
  bool isneg = wid >= P;
  int p = isneg ? wid - P : wid;
  int i = isneg ? ni[p] : pi[p];
  int j = isneg ? nj[p] : pj[p];
  short8 a = ((const short8*)(ZS1 + (size_t)i * HD))[lane];
  short8 b = ((const short8*)(ZS2 + (size_t)j * HD))[lane];
  float s = 0.f;
#pragma unroll
  for (int t = 0; t < 8; ++t)
    s = fmaf(bf2f((unsigned short)a[t]), bf2f((unsigned short)b[t]), s);
#pragma unroll
  for (int off = 1; off < 64; off <<= 1) s += __shfl_xor(s, off);
  if (lane == 0) {
    float ip = isneg ? -s : s;
    lsig[wid] = fminf(ip, 0.f) - log1pf(expf(-fabsf(ip)));
  }
}

// ---------------- parallel partial reduction -> per-block partials ----------------
#define RED_BLOCKS 128
__global__ __launch_bounds__(256) void reduce_partial(const float* __restrict__ acc,
                                                      const float* __restrict__ lsig,
                                                      int P, float* __restrict__ part) {
  __shared__ float red[6][4];
  int tid = threadIdx.x;
  int gid = blockIdx.x * 256 + tid;
  int stride = gridDim.x * 256;
  float loc[6] = {0.f, 0.f, 0.f, 0.f, 0.f, 0.f};
  for (int idx = gid; idx < 2 * NR; idx += stride) {
    int l = idx >> 12, i = idx & (NR - 1);
    const float* base = acc + (size_t)l * 4 * NR;
    float t0 = logf(base[NR + i] / (base[i] + 1e-8f));              // log(rp/rs)
    float t1 = logf(base[3 * NR + i] / (base[2 * NR + i] + 1e-8f)); // log(cp/cs)
    if (l == 0) { loc[0] += t0; loc[1] += t1; }
    else        { loc[2] += t0; loc[3] += t1; }
  }
  for (int i = gid; i < P; i += stride) loc[4] += lsig[i];
  for (int i = gid; i < P; i += stride) loc[5] += lsig[P + i];
  int wv = tid >> 6, ln = tid & 63;
#pragma unroll
  for (int q = 0; q < 6; ++q) {
    float s = loc[q];
#pragma unroll
    for (int off = 1; off < 64; off <<= 1) s += __shfl_xor(s, off);
    if (ln == 0) red[q][wv] = s;
  }
  __syncthreads();
  if (tid < 6) part[blockIdx.x * 6 + tid] = red[tid][0] + red[tid][1] + red[tid][2] + red[tid][3];
}

// ---------------- combine partials -> scalar (1 wave) ----------------
__global__ __launch_bounds__(64) void finalize2(const float* __restrict__ part,
                                                int P, float* __restrict__ out) {
  int ln = threadIdx.x;  // 0..63
  float t[6];
#pragma unroll
  for (int q = 0; q < 6; ++q) {
    float s = part[ln * 6 + q] + part[(ln + 64) * 6 + q];
#pragma unroll
    for (int off = 1; off < 64; off <<= 1) s += __shfl_xor(s, off);
    t[q] = s;
  }
  if (ln == 0) {
    float loss1 = LAMBDA * (-t[0] / (float)NR) + (1.f - LAMBDA) * (-t[1] / (float)NR);
    float loss2 = LAMBDA * (-t[2] / (float)NR) + (1.f - LAMBDA) * (-t[3] / (float)NR);
    float loss_main = -(t[4] / (float)P) + (t[5] / (float)P);
    out[0] = loss_main + loss1 + loss2;
  }
}

extern "C" void kernel_launch(void* const* d_in, const int* in_sizes, int n_in,
                              void* d_out, int out_size, void* d_ws, size_t ws_size,
                              hipStream_t stream) {
  const float* z_mp1 = (const float*)d_in[0];
  const float* z_sc1 = (const float*)d_in[1];
  const float* pos1 = (const float*)d_in[2];
  const float* z_mp2 = (const float*)d_in[3];
  const float* z_sc2 = (const float*)d_in[4];
  const float* pos2 = (const float*)d_in[5];
  const float* W1 = (const float*)d_in[6];
  const float* b1 = (const float*)d_in[7];
  const float* W2 = (const float*)d_in[8];
  const float* b2 = (const float*)d_in[9];
  const int* pi = (const int*)d_in[10];
  const int* pj = (const int*)d_in[11];
  const int* ni = (const int*)d_in[12];
  const int* nj = (const int*)d_in[13];
  const int P = in_sizes[10];

  char* ws = (char*)d_ws;
  float* ACC = (float*)(ws);                                   // 256KB zeroed: [0,8*4096) acc
  float* PART = ACC + 8 * 4096;                                // 128*6 f32 (fully overwritten)
  float* INV = (float*)(ws + 260 * 1024);                      // 2*4096 f32
  float* LSIG = (float*)(ws + 300 * 1024);                     // 2P f32 (~538KB, ends <1MB)
  unsigned short* W1b = (unsigned short*)(ws + 1024 * 1024);       // 512KB
  unsigned short* W2b = (unsigned short*)(ws + 1536 * 1024);       // 512KB
  unsigned short* ZB0 = (unsigned short*)(ws + 2 * 1024 * 1024);   // 4MB
  unsigned short* ZB1 = (unsigned short*)(ws + 6 * 1024 * 1024);   // 4MB
  unsigned short* ZSB1 = (unsigned short*)(ws + 10 * 1024 * 1024); // 4MB bf16 zsum1
  unsigned short* ZSB2 = (unsigned short*)(ws + 14 * 1024 * 1024); // 4MB bf16 zsum2
  unsigned short* HBm = (unsigned short*)(ws + 10 * 1024 * 1024);  // alias ZSB1 (pair done first)
  unsigned short* HBs = (unsigned short*)(ws + 14 * 1024 * 1024);  // alias ZSB2
  unsigned short* PAb = (unsigned short*)(ws + 18 * 1024 * 1024);  // 4MB
  unsigned short* PBb = (unsigned short*)(ws + 22 * 1024 * 1024);  // 4MB
  unsigned long long* PU1 = (unsigned long long*)(ws + 26 * 1024 * 1024);  // 2MB bitmask
  unsigned long long* PU2 = (unsigned long long*)(ws + 28 * 1024 * 1024);  // 2MB bitmask

  hipMemsetAsync(ACC, 0, 16 * 4096 * sizeof(float), stream);

  cast_bf16<<<256, 256, 0, stream>>>(W1, W1b, 512 * 512 / 4);
  cast_bf16<<<256, 256, 0, stream>>>(W2, W2b, 512 * 512 / 4);
  addz_bf<<<2048, 256, 0, stream>>>(z_mp1, z_sc1, ZSB1, NR * HD / 4);
  addz_bf<<<2048, 256, 0, stream>>>(z_mp2, z_sc2, ZSB2, NR * HD / 4);
  pair_logsig<<<(2 * P + 3) / 4, 256, 0, stream>>>(ZSB1, ZSB2, pi, pj, ni, nj, P, LSIG);
  pos_pack<<<2048, 256, 0, stream>>>(pos1, PU1);
  pos_pack<<<2048, 256, 0, stream>>>(pos2, PU2);

  dim3 gP(4, 64);    // proj: N/128 x (2 streams * M/128)
  dim3 gS(32, 32);   // sim: 4096/128 each dim
  for (int ll = 0; ll < 2; ++ll) {
    const float* zm = ll ? z_mp2 : z_mp1;
    const float* zs = ll ? z_sc2 : z_sc1;
    const unsigned int* bm = (const unsigned int*)(ll ? PU2 : PU1);
    cast_bf16<<<2048, 256, 0, stream>>>(zm, ZB0, NR * HD / 4);
    cast_bf16<<<2048, 256, 0, stream>>>(zs, ZB1, NR * HD / 4);
    proj_mfma<true><<<gP, 256, 0, stream>>>(ZB0, ZB1, W1b, b1, HBm, HBs);
    proj_mfma<false><<<gP, 256, 0, stream>>>(HBm, HBs, W2b, b2, PAb, PBb);
    rownorm_bf<<<1024, 256, 0, stream>>>(PAb, INV, NR);
    rownorm_bf<<<1024, 256, 0, stream>>>(PBb, INV + 4096, NR);
    sim_mfma<<<gS, 256, 0, stream>>>(PAb, PBb, INV, INV + 4096, bm,
                                     ACC + (size_t)(ll * 4 + 0) * 4096, ACC + (size_t)(ll * 4 + 1) * 4096,
                                     ACC + (size_t)(ll * 4 + 2) * 4096, ACC + (size_t)(ll * 4 + 3) * 4096);
  }
  reduce_partial<<<RED_BLOCKS, 256, 0, stream>>>(ACC, LSIG, P, PART);
  finalize2<<<1, 64, 0, stream>>>(PART, P, (float*)d_out);
}

// Round 11
// 417.861 us; speedup vs baseline: 1.0331x; 1.0331x over previous
//
#include <hip/hip_runtime.h>
#include <math.h>

#define TAU_INV 1.25f
#define LOG2E 1.4426950408889634f
#define LAMBDA 0.5f
#define NR 4096
#define HD 512

typedef __attribute__((ext_vector_type(8))) short short8;
typedef __attribute__((ext_vector_type(4))) float f32x4;
typedef __attribute__((ext_vector_type(4))) unsigned short ushort4v;

#if defined(__has_builtin)
#if __has_builtin(__builtin_amdgcn_exp2f)
#define FEXP2 __builtin_amdgcn_exp2f
#endif
#endif
#ifndef FEXP2
#define FEXP2 exp2f
#endif

static __device__ __forceinline__ unsigned short f2bf(float f) {
  unsigned int u = __float_as_uint(f);
  u += 0x7fff + ((u >> 16) & 1);   // RNE
  return (unsigned short)(u >> 16);
}
static __device__ __forceinline__ float bf2f(unsigned short s) {
  return __uint_as_float(((unsigned int)s) << 16);
}

// ---------------- prep: W1/W2 casts + zsum1/zsum2 (bf16), one launch ----------------
// seg layout (float4 items): [0,65536) W1; [65536,131072) W2; [131072,655360) addz1; [655360,1179648) addz2
__global__ __launch_bounds__(256) void prep(const float* __restrict__ W1, const float* __restrict__ W2,
                                            const float* __restrict__ zm1, const float* __restrict__ zs1,
                                            const float* __restrict__ zm2, const float* __restrict__ zs2,
                                            unsigned short* __restrict__ W1b, unsigned short* __restrict__ W2b,
                                            unsigned short* __restrict__ ZSB1, unsigned short* __restrict__ ZSB2) {
  int gid = blockIdx.x * 256 + threadIdx.x;
  if (gid < 131072) {
    const float* src = gid < 65536 ? W1 : W2;
    unsigned short* dst = gid < 65536 ? W1b : W2b;
    int i = gid & 65535;
    float4 v = ((const float4*)src)[i];
    ushort4v o;
    o.x = f2bf(v.x); o.y = f2bf(v.y); o.z = f2bf(v.z); o.w = f2bf(v.w);
    ((ushort4v*)dst)[i] = o;
  } else if (gid < 1179648) {
    int g = gid - 131072;
    const float* a = g < 524288 ? zm1 : zm2;
    const float* b = g < 524288 ? zs1 : zs2;
    unsigned short* o = g < 524288 ? ZSB1 : ZSB2;
    int i = g & 524287;
    float4 x = ((const float4*)a)[i], y = ((const float4*)b)[i];
    ushort4v r;
    r.x = f2bf(x.x + y.x); r.y = f2bf(x.y + y.y);
    r.z = f2bf(x.z + y.z); r.w = f2bf(x.w + y.w);
    ((ushort4v*)o)[i] = r;
  }
}

// ---------------- both z casts for one stream: zm->ZB0, zs->ZB1 ----------------
__global__ __launch_bounds__(256) void cast2_bf16(const float* __restrict__ zm,
                                                  const float* __restrict__ zs,
                                                  unsigned short* __restrict__ ZB0,
                                                  unsigned short* __restrict__ ZB1) {
  int gid = blockIdx.x * 256 + threadIdx.x;
  const float* src = gid < 524288 ? zm : zs;
  unsigned short* dst = gid < 524288 ? ZB0 : ZB1;
  int i = gid & 524287;
  float4 v = ((const float4*)src)[i];
  ushort4v o;
  o.x = f2bf(v.x); o.y = f2bf(v.y); o.z = f2bf(v.z); o.w = f2bf(v.w);
  ((ushort4v*)dst)[i] = o;
}

// ---------------- both pos -> bitmasks, one launch ----------------
__global__ __launch_bounds__(256) void pos_pack2(const float* __restrict__ pos1,
                                                 const float* __restrict__ pos2,
                                                 unsigned long long* __restrict__ b1,
                                                 unsigned long long* __restrict__ b2) {
  int lane = threadIdx.x & 63;
  int gw = (blockIdx.x * 256 + threadIdx.x) >> 6;
  int stride = (gridDim.x * 256) >> 6;
  const int nwords = NR * NR / 64;
  for (int w = gw; w < 2 * nwords; w += stride) {
    const float* pos = w < nwords ? pos1 : pos2;
    unsigned long long* bits = w < nwords ? b1 : b2;
    int ww = w < nwords ? w : w - nwords;
    float v = pos[(size_t)ww * 64 + lane];
    unsigned long long m = __ballot(v > 0.5f);
    if (lane == 0) bits[ww] = m;
  }
}

// ============ MFMA GEMM core macros (128x128 tile, BK=64, XOR-swizzled LDS) ============
#define GEMM_STAGE(Aptr, Bptr, rb, cb_, kb)                                                     \
  {                                                                                             \
    _Pragma("unroll") for (int q = 0; q < 4; ++q) {                                             \
      int r0 = q * 32 + w * 8;                                                                  \
      const char* sa = (const char*)(Aptr) + ((size_t)((rb) + r0 + lrow) << 10) + (kb)*128 + scb;\
      const char* sb = (const char*)(Bptr) + ((size_t)((cb_) + r0 + lrow) << 10) + (kb)*128 + scb;\
      __builtin_amdgcn_global_load_lds((const __attribute__((address_space(1))) unsigned int*)sa,\
          (__attribute__((address_space(3))) unsigned int*)(void*)((char*)As + r0 * 128), 16, 0, 0);\
      __builtin_amdgcn_global_load_lds((const __attribute__((address_space(1))) unsigned int*)sb,\
          (__attribute__((address_space(3))) unsigned int*)(void*)((char*)Bs + r0 * 128), 16, 0, 0);\
    }                                                                                           \
  }

#define GEMM_COMPUTE()                                                                          \
  {                                                                                             \
    _Pragma("unroll") for (int kk = 0; kk < 2; ++kk) {                                          \
      short8 av[4], bv[4];                                                                      \
      _Pragma("unroll") for (int mf = 0; mf < 4; ++mf) {                                        \
        int row = wr * 64 + mf * 16 + (l & 15);                                                 \
        int kbyte = ((kk * 64) + ((l >> 4) * 16)) ^ ((l & 7) << 4);                             \
        av[mf] = *(const short8*)((const char*)As + row * 128 + kbyte);                         \
      }                                                                                        \
      _Pragma("unroll") for (int nf = 0; nf < 4; ++nf) {                                        \
        int row = wc * 64 + nf * 16 + (l & 15);                                                 \
        int kbyte = ((kk * 64) + ((l >> 4) * 16)) ^ ((l & 7) << 4);                             \
        bv[nf] = *(const short8*)((const char*)Bs + row * 128 + kbyte);                         \
      }                                                                                        \
      _Pragma("unroll") for (int mf = 0; mf < 4; ++mf)                                          \
        _Pragma("unroll") for (int nf = 0; nf < 4; ++nf)                                        \
          acc[mf][nf] = __builtin_amdgcn_mfma_f32_16x16x32_bf16(av[mf], bv[nf], acc[mf][nf], 0, 0, 0);\
    }                                                                                           \
  }

// ---------------- proj GEMM: C = A @ W^T + bias (optional ELU), bf16 in/out, 2 streams ----------------
template <bool DO_ELU>
__global__ __launch_bounds__(256) void proj_mfma(const unsigned short* __restrict__ A0,
                                                 const unsigned short* __restrict__ A1,
                                                 const unsigned short* __restrict__ B,
                                                 const float* __restrict__ bias,
                                                 unsigned short* __restrict__ C0,
                                                 unsigned short* __restrict__ C1) {
  __shared__ unsigned short As[128 * 64];
  __shared__ unsigned short Bs[128 * 64];
  const int tid = threadIdx.x;
  const int l = tid & 63, w = tid >> 6;
  const int wr = w >> 1, wc = w & 1;
  const int stream_id = blockIdx.y >> 5;
  const int rowbase = (blockIdx.y & 31) * 128;
  const int colbase = blockIdx.x * 128;
  const unsigned short* A = stream_id ? A1 : A0;
  unsigned short* C = stream_id ? C1 : C0;
  const int lrow = l >> 3;
  const int scb = ((l & 7) ^ lrow) << 4;

  f32x4 acc[4][4];
#pragma unroll
  for (int i = 0; i < 4; ++i)
#pragma unroll
    for (int j = 0; j < 4; ++j) acc[i][j] = (f32x4){0.f, 0.f, 0.f, 0.f};

  for (int kb = 0; kb < 8; ++kb) {
    GEMM_STAGE(A, B, rowbase, colbase, kb);
    __syncthreads();
    GEMM_COMPUTE();
    __syncthreads();
  }

  const int cq = l >> 4, cn = l & 15;
#pragma unroll
  for (int mf = 0; mf < 4; ++mf) {
#pragma unroll
    for (int nf = 0; nf < 4; ++nf) {
      int col = colbase + wc * 64 + nf * 16 + cn;
      float bb = bias[col];
#pragma unroll
      for (int j = 0; j < 4; ++j) {
        int row = rowbase + wr * 64 + mf * 16 + cq * 4 + j;
        float v = acc[mf][nf][j] + bb;
        if (DO_ELU) v = v > 0.f ? v : expm1f(v);
        C[(size_t)row * HD + col] = f2bf(v);
      }
    }
  }
}

// ---------------- row inv-norms for BOTH projected matrices, one launch ----------------
__global__ __launch_bounds__(256) void rownorm2_bf(const unsigned short* __restrict__ ZA,
                                                   const unsigned short* __restrict__ ZB,
                                                   float* __restrict__ inv) {
  int wid = blockIdx.x * 4 + (threadIdx.x >> 6);   // 0..8191
  int lane = threadIdx.x & 63;
  if (wid >= 2 * NR) return;
  const unsigned short* Z = wid < NR ? ZA : ZB;
  int r = wid < NR ? wid : wid - NR;
  short8 v = ((const short8*)(Z + (size_t)r * HD))[lane];
  float s = 0.f;
#pragma unroll
  for (int j = 0; j < 8; ++j) {
    float f = bf2f((unsigned short)v[j]);
    s += f * f;
  }
#pragma unroll
  for (int off = 1; off < 64; off <<= 1) s += __shfl_xor(s, off);
  if (lane == 0) inv[wid] = 1.f / sqrtf(s);
}

// ---------------- fused similarity (MFMA) + fast-exp + bitmask pos row/col reductions ----------------
__global__ __launch_bounds__(256) void sim_mfma(const unsigned short* __restrict__ PA,
                                                const unsigned short* __restrict__ PB,
                                                const float* __restrict__ invA,
                                                const float* __restrict__ invB,
                                                const unsigned int* __restrict__ BM,  // bitmask, row*128 u32s
                                                float* __restrict__ accRS,
                                                float* __restrict__ accRP,
                                                float* __restrict__ accCS,
                                                float* __restrict__ accCP) {
  __shared__ unsigned short As[128 * 64];
  __shared__ unsigned short Bs[128 * 64];
  const int tid = threadIdx.x;
  const int l = tid & 63, w = tid >> 6;
  const int wr = w >> 1, wc = w & 1;
  const int rowbase = blockIdx.y * 128;
  const int colbase = blockIdx.x * 128;
  const int lrow = l >> 3;
  const int scb = ((l & 7) ^ lrow) << 4;

  f32x4 acc[4][4];
#pragma unroll
  for (int i = 0; i < 4; ++i)
#pragma unroll
    for (int j = 0; j < 4; ++j) acc[i][j] = (f32x4){0.f, 0.f, 0.f, 0.f};

  for (int kb = 0; kb < 8; ++kb) {
    GEMM_STAGE(PA, PB, rowbase, colbase, kb);
    __syncthreads();
    GEMM_COMPUTE();
    __syncthreads();
  }

  const int cq = l >> 4, cn = l & 15;
  // scales: fold tau^-1 * log2(e) into row scale; m = 2^(dot*srA*scB)
  float sr[4][4], sc[4];
#pragma unroll
  for (int mf = 0; mf < 4; ++mf) {
    float4 iv = *(const float4*)(invA + rowbase + wr * 64 + mf * 16 + cq * 4);
    sr[mf][0] = iv.x * (TAU_INV * LOG2E); sr[mf][1] = iv.y * (TAU_INV * LOG2E);
    sr[mf][2] = iv.z * (TAU_INV * LOG2E); sr[mf][3] = iv.w * (TAU_INV * LOG2E);
  }
#pragma unroll
  for (int nf = 0; nf < 4; ++nf) sc[nf] = invB[colbase + wc * 64 + nf * 16 + cn];

#pragma unroll
  for (int mf = 0; mf < 4; ++mf)
#pragma unroll
    for (int nf = 0; nf < 4; ++nf)
#pragma unroll
      for (int j = 0; j < 4; ++j)
        acc[mf][nf][j] = FEXP2(acc[mf][nf][j] * sr[mf][j] * sc[nf]);

  // row sums + pos-weighted row sums (pos bits from BM[row][col])
#pragma unroll
  for (int mf = 0; mf < 4; ++mf) {
    float rs[4] = {0.f, 0.f, 0.f, 0.f}, rp[4] = {0.f, 0.f, 0.f, 0.f};
#pragma unroll
    for (int j = 0; j < 4; ++j) {
      int row = rowbase + wr * 64 + mf * 16 + cq * 4 + j;
      const unsigned int* bmr = BM + (size_t)row * 128 + (colbase >> 5) + wc * 2;
      unsigned int w0 = bmr[0], w1 = bmr[1];   // cols [base,base+32), [base+32,base+64)
#pragma unroll
      for (int nf = 0; nf < 4; ++nf) {
        float m = acc[mf][nf][j];
        rs[j] += m;
        unsigned int wsel = (nf < 2) ? w0 : w1;
        if ((wsel >> ((nf * 16 + cn) & 31)) & 1) rp[j] += m;
      }
    }
#pragma unroll
    for (int off = 1; off < 16; off <<= 1) {
#pragma unroll
      for (int j = 0; j < 4; ++j) { rs[j] += __shfl_xor(rs[j], off); rp[j] += __shfl_xor(rp[j], off); }
    }
    if (cn == 0) {
#pragma unroll
      for (int j = 0; j < 4; ++j) {
        int row = rowbase + wr * 64 + mf * 16 + cq * 4 + j;
        atomicAdd(&accRS[row], rs[j]);
        atomicAdd(&accRP[row], rp[j]);
      }
    }
  }

  // col sums + pos^T-weighted col sums (pos bits from BM[col][row])
  float cs[4] = {0.f, 0.f, 0.f, 0.f}, cp[4] = {0.f, 0.f, 0.f, 0.f};
#pragma unroll
  for (int nf = 0; nf < 4; ++nf) {
    int col = colbase + wc * 64 + nf * 16 + cn;
    const unsigned int* bmc = BM + (size_t)col * 128 + (rowbase >> 5) + wr * 2;
    unsigned int w0 = bmc[0], w1 = bmc[1];     // rows [base,base+32), [base+32,base+64)
#pragma unroll
    for (int mf = 0; mf < 4; ++mf) {
      unsigned int wsel = (mf < 2) ? w0 : w1;
#pragma unroll
      for (int j = 0; j < 4; ++j) {
        float m = acc[mf][nf][j];
        cs[nf] += m;
        if ((wsel >> ((mf * 16 + cq * 4 + j) & 31)) & 1) cp[nf] += m;
      }
    }
  }
#pragma unroll
  for (int off = 16; off < 64; off <<= 1) {
#pragma unroll
    for (int nf = 0; nf < 4; ++nf) { cs[nf] += __shfl_xor(cs[nf], off); cp[nf] += __shfl_xor(cp[nf], off); }
  }
  if (cq == 0) {
#pragma unroll
    for (int nf = 0; nf < 4; ++nf) {
      int col = colbase + wc * 64 + nf * 16 + cn;
      atomicAdd(&accCS[col], cs[nf]);
      atomicAdd(&accCP[col], cp[nf]);
    }
  }
}

// ---------------- pair dot + log-sigmoid (bf16 zsum gathers) ----------------
__global__ __launch_bounds__(256) void pair_logsig(const unsigned short* __restrict__ ZS1,
                                                   const unsigned short* __restrict__ ZS2,
                                                   const int* __restrict__ pi,
                                                   const int* __restrict__ pj,
                                                   const int* __restrict__ ni,
                                                   const int* __restrict__ nj,
                                                   int P, float* __restrict__ lsig) {
  int wid = blockIdx.x * 4 + (threadIdx.x >> 6);
  int lane = threadIdx.x & 63;
  if (wid >= 2 * P) return;
  bool isneg = wid >= P;
  int p = isneg ? wid - P : wid;
  int i = isneg ? ni[p] : pi[p];
  int j = isneg ? nj[p] : pj[p];
  short8 a = ((const short8*)(ZS1 + (size_t)i * HD))[lane];
  short8 b = ((const short8*)(ZS2 + (size_t)j * HD))[lane];
  float s = 0.f;
#pragma unroll
  for (int t = 0; t < 8; ++t)
    s = fmaf(bf2f((unsigned short)a[t]), bf2f((unsigned short)b[t]), s);
#pragma unroll
  for (int off = 1; off < 64; off <<= 1) s += __shfl_xor(s, off);
  if (lane == 0) {
    float ip = isneg ? -s : s;
    lsig[wid] = fminf(ip, 0.f) - log1pf(expf(-fabsf(ip)));
  }
}

// ---------------- parallel partial reduction -> per-block partials ----------------
#define RED_BLOCKS 128
__global__ __launch_bounds__(256) void reduce_partial(const float* __restrict__ acc,
                                                      const float* __restrict__ lsig,
                                                      int P, float* __restrict__ part) {
  __shared__ float red[6][4];
  int tid = threadIdx.x;
  int gid = blockIdx.x * 256 + tid;
  int stride = gridDim.x * 256;
  float loc[6] = {0.f, 0.f, 0.f, 0.f, 0.f, 0.f};
  for (int idx = gid; idx < 2 * NR; idx += stride) {
    int l = idx >> 12, i = idx & (NR - 1);
    const float* base = acc + (size_t)l * 4 * NR;
    float t0 = logf(base[NR + i] / (base[i] + 1e-8f));              // log(rp/rs)
    float t1 = logf(base[3 * NR + i] / (base[2 * NR + i] + 1e-8f)); // log(cp/cs)
    if (l == 0) { loc[0] += t0; loc[1] += t1; }
    else        { loc[2] += t0; loc[3] += t1; }
  }
  for (int i = gid; i < P; i += stride) loc[4] += lsig[i];
  for (int i = gid; i < P; i += stride) loc[5] += lsig[P + i];
  int wv = tid >> 6, ln = tid & 63;
#pragma unroll
  for (int q = 0; q < 6; ++q) {
    float s = loc[q];
#pragma unroll
    for (int off = 1; off < 64; off <<= 1) s += __shfl_xor(s, off);
    if (ln == 0) red[q][wv] = s;
  }
  __syncthreads();
  if (tid < 6) part[blockIdx.x * 6 + tid] = red[tid][0] + red[tid][1] + red[tid][2] + red[tid][3];
}

// ---------------- combine partials -> scalar (1 wave) ----------------
__global__ __launch_bounds__(64) void finalize2(const float* __restrict__ part,
                                                int P, float* __restrict__ out) {
  int ln = threadIdx.x;  // 0..63
  float t[6];
#pragma unroll
  for (int q = 0; q < 6; ++q) {
    float s = part[ln * 6 + q] + part[(ln + 64) * 6 + q];
#pragma unroll
    for (int off = 1; off < 64; off <<= 1) s += __shfl_xor(s, off);
    t[q] = s;
  }
  if (ln == 0) {
    float loss1 = LAMBDA * (-t[0] / (float)NR) + (1.f - LAMBDA) * (-t[1] / (float)NR);
    float loss2 = LAMBDA * (-t[2] / (float)NR) + (1.f - LAMBDA) * (-t[3] / (float)NR);
    float loss_main = -(t[4] / (float)P) + (t[5] / (float)P);
    out[0] = loss_main + loss1 + loss2;
  }
}

extern "C" void kernel_launch(void* const* d_in, const int* in_sizes, int n_in,
                              void* d_out, int out_size, void* d_ws, size_t ws_size,
                              hipStream_t stream) {
  const float* z_mp1 = (const float*)d_in[0];
  const float* z_sc1 = (const float*)d_in[1];
  const float* pos1 = (const float*)d_in[2];
  const float* z_mp2 = (const float*)d_in[3];
  const float* z_sc2 = (const float*)d_in[4];
  const float* pos2 = (const float*)d_in[5];
  const float* W1 = (const float*)d_in[6];
  const float* b1 = (const float*)d_in[7];
  const float* W2 = (const float*)d_in[8];
  const float* b2 = (const float*)d_in[9];
  const int* pi = (const int*)d_in[10];
  const int* pj = (const int*)d_in[11];
  const int* ni = (const int*)d_in[12];
  const int* nj = (const int*)d_in[13];
  const int P = in_sizes[10];

  char* ws = (char*)d_ws;
  float* ACC = (float*)(ws);                                   // 256KB zeroed: [0,8*4096) acc
  float* PART = ACC + 8 * 4096;                                // 128*6 f32 (fully overwritten)
  float* INV = (float*)(ws + 260 * 1024);                      // 2*4096 f32
  float* LSIG = (float*)(ws + 300 * 1024);                     // 2P f32 (~538KB, ends <1MB)
  unsigned short* W1b = (unsigned short*)(ws + 1024 * 1024);       // 512KB
  unsigned short* W2b = (unsigned short*)(ws + 1536 * 1024);       // 512KB
  unsigned short* ZB0 = (unsigned short*)(ws + 2 * 1024 * 1024);   // 4MB
  unsigned short* ZB1 = (unsigned short*)(ws + 6 * 1024 * 1024);   // 4MB
  unsigned short* ZSB1 = (unsigned short*)(ws + 10 * 1024 * 1024); // 4MB bf16 zsum1
  unsigned short* ZSB2 = (unsigned short*)(ws + 14 * 1024 * 1024); // 4MB bf16 zsum2
  unsigned short* HBm = (unsigned short*)(ws + 10 * 1024 * 1024);  // alias ZSB1 (pair done first)
  unsigned short* HBs = (unsigned short*)(ws + 14 * 1024 * 1024);  // alias ZSB2
  unsigned short* PAb = (unsigned short*)(ws + 18 * 1024 * 1024);  // 4MB
  unsigned short* PBb = (unsigned short*)(ws + 22 * 1024 * 1024);  // 4MB
  unsigned long long* PU1 = (unsigned long long*)(ws + 26 * 1024 * 1024);  // 2MB bitmask
  unsigned long long* PU2 = (unsigned long long*)(ws + 28 * 1024 * 1024);  // 2MB bitmask

  hipMemsetAsync(ACC, 0, 16 * 4096 * sizeof(float), stream);

  prep<<<4608, 256, 0, stream>>>(W1, W2, z_mp1, z_sc1, z_mp2, z_sc2, W1b, W2b, ZSB1, ZSB2);
  pair_logsig<<<(2 * P + 3) / 4, 256, 0, stream>>>(ZSB1, ZSB2, pi, pj, ni, nj, P, LSIG);
  pos_pack2<<<2048, 256, 0, stream>>>(pos1, pos2, PU1, PU2);

  dim3 gP(4, 64);    // proj: N/128 x (2 streams * M/128)
  dim3 gS(32, 32);   // sim: 4096/128 each dim
  for (int ll = 0; ll < 2; ++ll) {
    const float* zm = ll ? z_mp2 : z_mp1;
    const float* zs = ll ? z_sc2 : z_sc1;
    const unsigned int* bm = (const unsigned int*)(ll ? PU2 : PU1);
    cast2_bf16<<<4096, 256, 0, stream>>>(zm, zs, ZB0, ZB1);
    proj_mfma<true><<<gP, 256, 0, stream>>>(ZB0, ZB1, W1b, b1, HBm, HBs);
    proj_mfma<false><<<gP, 256, 0, stream>>>(HBm, HBs, W2b, b2, PAb, PBb);
    rownorm2_bf<<<2048, 256, 0, stream>>>(PAb, PBb, INV);
    sim_mfma<<<gS, 256, 0, stream>>>(PAb, PBb, INV, INV + 4096, bm,
                                     ACC + (size_t)(ll * 4 + 0) * 4096, ACC + (size_t)(ll * 4 + 1) * 4096,
                                     ACC + (size_t)(ll * 4 + 2) * 4096, ACC + (size_t)(ll * 4 + 3) * 4096);
  }
  reduce_partial<<<RED_BLOCKS, 256, 0, stream>>>(ACC, LSIG, P, PART);
  finalize2<<<1, 64, 0, stream>>>(PART, P, (float*)d_out);
}

// Round 12
// 404.520 us; speedup vs baseline: 1.0672x; 1.0330x over previous
//
#include <hip/hip_runtime.h>
#include <math.h>

#define TAU_INV 1.25f
#define LOG2E 1.4426950408889634f
#define LAMBDA 0.5f
#define NR 4096
#define HD 512

typedef __attribute__((ext_vector_type(8))) short short8;
typedef __attribute__((ext_vector_type(4))) float f32x4;
typedef __attribute__((ext_vector_type(4))) unsigned short ushort4v;

#if defined(__has_builtin)
#if __has_builtin(__builtin_amdgcn_exp2f)
#define FEXP2 __builtin_amdgcn_exp2f
#endif
#endif
#ifndef FEXP2
#define FEXP2 exp2f
#endif

static __device__ __forceinline__ unsigned short f2bf(float f) {
  unsigned int u = __float_as_uint(f);
  u += 0x7fff + ((u >> 16) & 1);   // RNE
  return (unsigned short)(u >> 16);
}
static __device__ __forceinline__ float bf2f(unsigned short s) {
  return __uint_as_float(((unsigned int)s) << 16);
}

// ---------------- prep: W1/W2 casts + zsum1/zsum2 (bf16), one launch ----------------
__global__ __launch_bounds__(256) void prep(const float* __restrict__ W1, const float* __restrict__ W2,
                                            const float* __restrict__ zm1, const float* __restrict__ zs1,
                                            const float* __restrict__ zm2, const float* __restrict__ zs2,
                                            unsigned short* __restrict__ W1b, unsigned short* __restrict__ W2b,
                                            unsigned short* __restrict__ ZSB1, unsigned short* __restrict__ ZSB2) {
  int gid = blockIdx.x * 256 + threadIdx.x;
  if (gid < 131072) {
    const float* src = gid < 65536 ? W1 : W2;
    unsigned short* dst = gid < 65536 ? W1b : W2b;
    int i = gid & 65535;
    float4 v = ((const float4*)src)[i];
    ushort4v o;
    o.x = f2bf(v.x); o.y = f2bf(v.y); o.z = f2bf(v.z); o.w = f2bf(v.w);
    ((ushort4v*)dst)[i] = o;
  } else if (gid < 1179648) {
    int g = gid - 131072;
    const float* a = g < 524288 ? zm1 : zm2;
    const float* b = g < 524288 ? zs1 : zs2;
    unsigned short* o = g < 524288 ? ZSB1 : ZSB2;
    int i = g & 524287;
    float4 x = ((const float4*)a)[i], y = ((const float4*)b)[i];
    ushort4v r;
    r.x = f2bf(x.x + y.x); r.y = f2bf(x.y + y.y);
    r.z = f2bf(x.z + y.z); r.w = f2bf(x.w + y.w);
    ((ushort4v*)o)[i] = r;
  }
}

// ---------------- both z casts for one stream: zm->ZB0, zs->ZB1 ----------------
__global__ __launch_bounds__(256) void cast2_bf16(const float* __restrict__ zm,
                                                  const float* __restrict__ zs,
                                                  unsigned short* __restrict__ ZB0,
                                                  unsigned short* __restrict__ ZB1) {
  int gid = blockIdx.x * 256 + threadIdx.x;
  const float* src = gid < 524288 ? zm : zs;
  unsigned short* dst = gid < 524288 ? ZB0 : ZB1;
  int i = gid & 524287;
  float4 v = ((const float4*)src)[i];
  ushort4v o;
  o.x = f2bf(v.x); o.y = f2bf(v.y); o.z = f2bf(v.z); o.w = f2bf(v.w);
  ((ushort4v*)dst)[i] = o;
}

// ---------------- both pos -> bitmasks, float4 loads + 16-lane OR-reduce ----------------
// Each wave-iteration packs one 256-element block (4 u64 words).
// lane l loads elements [blk*256 + l*4, +4); word j = nibbles of lanes 16j..16j+15.
__global__ __launch_bounds__(256) void pos_pack2(const float* __restrict__ pos1,
                                                 const float* __restrict__ pos2,
                                                 unsigned long long* __restrict__ b1,
                                                 unsigned long long* __restrict__ b2) {
  int lane = threadIdx.x & 63;
  int gw = (blockIdx.x * 256 + threadIdx.x) >> 6;
  int stride = (gridDim.x * 256) >> 6;
  const int nblk = NR * NR / 256;  // 65536 per matrix
  for (int w4 = gw; w4 < 2 * nblk; w4 += stride) {
    const float* pos = w4 < nblk ? pos1 : pos2;
    unsigned long long* bits = w4 < nblk ? b1 : b2;
    int ww = w4 < nblk ? w4 : w4 - nblk;
    float4 v = ((const float4*)pos)[(size_t)ww * 64 + lane];
    unsigned int nib = (v.x > 0.5f ? 1u : 0u) | (v.y > 0.5f ? 2u : 0u) |
                       (v.z > 0.5f ? 4u : 0u) | (v.w > 0.5f ? 8u : 0u);
    unsigned long long val = (unsigned long long)nib << (4 * (lane & 15));
#pragma unroll
    for (int off = 1; off < 16; off <<= 1) val |= __shfl_xor(val, off);
    if ((lane & 15) == 0) bits[(size_t)ww * 4 + (lane >> 4)] = val;
  }
}

// ============ MFMA GEMM core macros (128x128 tile, BK=64, XOR-swizzled LDS) ============
#define GEMM_STAGE(Aptr, Bptr, rb, cb_, kb)                                                     \
  {                                                                                             \
    _Pragma("unroll") for (int q = 0; q < 4; ++q) {                                             \
      int r0 = q * 32 + w * 8;                                                                  \
      const char* sa = (const char*)(Aptr) + ((size_t)((rb) + r0 + lrow) << 10) + (kb)*128 + scb;\
      const char* sb = (const char*)(Bptr) + ((size_t)((cb_) + r0 + lrow) << 10) + (kb)*128 + scb;\
      __builtin_amdgcn_global_load_lds((const __attribute__((address_space(1))) unsigned int*)sa,\
          (__attribute__((address_space(3))) unsigned int*)(void*)((char*)As + r0 * 128), 16, 0, 0);\
      __builtin_amdgcn_global_load_lds((const __attribute__((address_space(1))) unsigned int*)sb,\
          (__attribute__((address_space(3))) unsigned int*)(void*)((char*)Bs + r0 * 128), 16, 0, 0);\
    }                                                                                           \
  }

#define GEMM_COMPUTE()                                                                          \
  {                                                                                             \
    _Pragma("unroll") for (int kk = 0; kk < 2; ++kk) {                                          \
      short8 av[4], bv[4];                                                                      \
      _Pragma("unroll") for (int mf = 0; mf < 4; ++mf) {                                        \
        int row = wr * 64 + mf * 16 + (l & 15);                                                 \
        int kbyte = ((kk * 64) + ((l >> 4) * 16)) ^ ((l & 7) << 4);                             \
        av[mf] = *(const short8*)((const char*)As + row * 128 + kbyte);                         \
      }                                                                                        \
      _Pragma("unroll") for (int nf = 0; nf < 4; ++nf) {                                        \
        int row = wc * 64 + nf * 16 + (l & 15);                                                 \
        int kbyte = ((kk * 64) + ((l >> 4) * 16)) ^ ((l & 7) << 4);                             \
        bv[nf] = *(const short8*)((const char*)Bs + row * 128 + kbyte);                         \
      }                                                                                        \
      _Pragma("unroll") for (int mf = 0; mf < 4; ++mf)                                          \
        _Pragma("unroll") for (int nf = 0; nf < 4; ++nf)                                        \
          acc[mf][nf] = __builtin_amdgcn_mfma_f32_16x16x32_bf16(av[mf], bv[nf], acc[mf][nf], 0, 0, 0);\
    }                                                                                           \
  }

// ---------------- proj GEMM: C = A @ W^T + bias (optional ELU), bf16 in/out, 2 streams ----------------
template <bool DO_ELU>
__global__ __launch_bounds__(256) void proj_mfma(const unsigned short* __restrict__ A0,
                                                 const unsigned short* __restrict__ A1,
                                                 const unsigned short* __restrict__ B,
                                                 const float* __restrict__ bias,
                                                 unsigned short* __restrict__ C0,
                                                 unsigned short* __restrict__ C1) {
  __shared__ unsigned short As[128 * 64];
  __shared__ unsigned short Bs[128 * 64];
  const int tid = threadIdx.x;
  const int l = tid & 63, w = tid >> 6;
  const int wr = w >> 1, wc = w & 1;
  const int stream_id = blockIdx.y >> 5;
  const int rowbase = (blockIdx.y & 31) * 128;
  const int colbase = blockIdx.x * 128;
  const unsigned short* A = stream_id ? A1 : A0;
  unsigned short* C = stream_id ? C1 : C0;
  const int lrow = l >> 3;
  const int scb = ((l & 7) ^ lrow) << 4;

  f32x4 acc[4][4];
#pragma unroll
  for (int i = 0; i < 4; ++i)
#pragma unroll
    for (int j = 0; j < 4; ++j) acc[i][j] = (f32x4){0.f, 0.f, 0.f, 0.f};

  for (int kb = 0; kb < 8; ++kb) {
    GEMM_STAGE(A, B, rowbase, colbase, kb);
    __syncthreads();
    GEMM_COMPUTE();
    __syncthreads();
  }

  const int cq = l >> 4, cn = l & 15;
#pragma unroll
  for (int mf = 0; mf < 4; ++mf) {
#pragma unroll
    for (int nf = 0; nf < 4; ++nf) {
      int col = colbase + wc * 64 + nf * 16 + cn;
      float bb = bias[col];
#pragma unroll
      for (int j = 0; j < 4; ++j) {
        int row = rowbase + wr * 64 + mf * 16 + cq * 4 + j;
        float v = acc[mf][nf][j] + bb;
        if (DO_ELU) v = v > 0.f ? v : expm1f(v);
        C[(size_t)row * HD + col] = f2bf(v);
      }
    }
  }
}

// ---------------- row inv-norms for BOTH projected matrices, one launch ----------------
__global__ __launch_bounds__(256) void rownorm2_bf(const unsigned short* __restrict__ ZA,
                                                   const unsigned short* __restrict__ ZB,
                                                   float* __restrict__ inv) {
  int wid = blockIdx.x * 4 + (threadIdx.x >> 6);   // 0..8191
  int lane = threadIdx.x & 63;
  if (wid >= 2 * NR) return;
  const unsigned short* Z = wid < NR ? ZA : ZB;
  int r = wid < NR ? wid : wid - NR;
  short8 v = ((const short8*)(Z + (size_t)r * HD))[lane];
  float s = 0.f;
#pragma unroll
  for (int j = 0; j < 8; ++j) {
    float f = bf2f((unsigned short)v[j]);
    s += f * f;
  }
#pragma unroll
  for (int off = 1; off < 64; off <<= 1) s += __shfl_xor(s, off);
  if (lane == 0) inv[wid] = 1.f / sqrtf(s);
}

// ---------------- fused similarity (MFMA) + fast-exp + bitmask pos row/col reductions ----------------
__global__ __launch_bounds__(256) void sim_mfma(const unsigned short* __restrict__ PA,
                                                const unsigned short* __restrict__ PB,
                                                const float* __restrict__ invA,
                                                const float* __restrict__ invB,
                                                const unsigned int* __restrict__ BM,  // bitmask, row*128 u32s
                                                float* __restrict__ accRS,
                                                float* __restrict__ accRP,
                                                float* __restrict__ accCS,
                                                float* __restrict__ accCP) {
  __shared__ unsigned short As[128 * 64];
  __shared__ unsigned short Bs[128 * 64];
  const int tid = threadIdx.x;
  const int l = tid & 63, w = tid >> 6;
  const int wr = w >> 1, wc = w & 1;
  const int rowbase = blockIdx.y * 128;
  const int colbase = blockIdx.x * 128;
  const int lrow = l >> 3;
  const int scb = ((l & 7) ^ lrow) << 4;

  f32x4 acc[4][4];
#pragma unroll
  for (int i = 0; i < 4; ++i)
#pragma unroll
    for (int j = 0; j < 4; ++j) acc[i][j] = (f32x4){0.f, 0.f, 0.f, 0.f};

  for (int kb = 0; kb < 8; ++kb) {
    GEMM_STAGE(PA, PB, rowbase, colbase, kb);
    __syncthreads();
    GEMM_COMPUTE();
    __syncthreads();
  }

  const int cq = l >> 4, cn = l & 15;
  // scales: fold tau^-1 * log2(e) into row scale; m = 2^(dot*srA*scB)
  float sr[4][4], sc[4];
#pragma unroll
  for (int mf = 0; mf < 4; ++mf) {
    float4 iv = *(const float4*)(invA + rowbase + wr * 64 + mf * 16 + cq * 4);
    sr[mf][0] = iv.x * (TAU_INV * LOG2E); sr[mf][1] = iv.y * (TAU_INV * LOG2E);
    sr[mf][2] = iv.z * (TAU_INV * LOG2E); sr[mf][3] = iv.w * (TAU_INV * LOG2E);
  }
#pragma unroll
  for (int nf = 0; nf < 4; ++nf) sc[nf] = invB[colbase + wc * 64 + nf * 16 + cn];

#pragma unroll
  for (int mf = 0; mf < 4; ++mf)
#pragma unroll
    for (int nf = 0; nf < 4; ++nf)
#pragma unroll
      for (int j = 0; j < 4; ++j)
        acc[mf][nf][j] = FEXP2(acc[mf][nf][j] * sr[mf][j] * sc[nf]);

  // row sums + pos-weighted row sums (pos bits from BM[row][col])
#pragma unroll
  for (int mf = 0; mf < 4; ++mf) {
    float rs[4] = {0.f, 0.f, 0.f, 0.f}, rp[4] = {0.f, 0.f, 0.f, 0.f};
#pragma unroll
    for (int j = 0; j < 4; ++j) {
      int row = rowbase + wr * 64 + mf * 16 + cq * 4 + j;
      const unsigned int* bmr = BM + (size_t)row * 128 + (colbase >> 5) + wc * 2;
      unsigned int w0 = bmr[0], w1 = bmr[1];   // cols [base,base+32), [base+32,base+64)
#pragma unroll
      for (int nf = 0; nf < 4; ++nf) {
        float m = acc[mf][nf][j];
        rs[j] += m;
        unsigned int wsel = (nf < 2) ? w0 : w1;
        if ((wsel >> ((nf * 16 + cn) & 31)) & 1) rp[j] += m;
      }
    }
#pragma unroll
    for (int off = 1; off < 16; off <<= 1) {
#pragma unroll
      for (int j = 0; j < 4; ++j) { rs[j] += __shfl_xor(rs[j], off); rp[j] += __shfl_xor(rp[j], off); }
    }
    if (cn == 0) {
#pragma unroll
      for (int j = 0; j < 4; ++j) {
        int row = rowbase + wr * 64 + mf * 16 + cq * 4 + j;
        atomicAdd(&accRS[row], rs[j]);
        atomicAdd(&accRP[row], rp[j]);
      }
    }
  }

  // col sums + pos^T-weighted col sums (pos bits from BM[col][row])
  float cs[4] = {0.f, 0.f, 0.f, 0.f}, cp[4] = {0.f, 0.f, 0.f, 0.f};
#pragma unroll
  for (int nf = 0; nf < 4; ++nf) {
    int col = colbase + wc * 64 + nf * 16 + cn;
    const unsigned int* bmc = BM + (size_t)col * 128 + (rowbase >> 5) + wr * 2;
    unsigned int w0 = bmc[0], w1 = bmc[1];     // rows [base,base+32), [base+32,base+64)
#pragma unroll
    for (int mf = 0; mf < 4; ++mf) {
      unsigned int wsel = (mf < 2) ? w0 : w1;
#pragma unroll
      for (int j = 0; j < 4; ++j) {
        float m = acc[mf][nf][j];
        cs[nf] += m;
        if ((wsel >> ((mf * 16 + cq * 4 + j) & 31)) & 1) cp[nf] += m;
      }
    }
  }
#pragma unroll
  for (int off = 16; off < 64; off <<= 1) {
#pragma unroll
    for (int nf = 0; nf < 4; ++nf) { cs[nf] += __shfl_xor(cs[nf], off); cp[nf] += __shfl_xor(cp[nf], off); }
  }
  if (cq == 0) {
#pragma unroll
    for (int nf = 0; nf < 4; ++nf) {
      int col = colbase + wc * 64 + nf * 16 + cn;
      atomicAdd(&accCS[col], cs[nf]);
      atomicAdd(&accCP[col], cp[nf]);
    }
  }
}

// ---------------- pair dot + log-sigmoid (bf16 zsum gathers) ----------------
__global__ __launch_bounds__(256) void pair_logsig(const unsigned short* __restrict__ ZS1,
                                                   const unsigned short* __restrict__ ZS2,
                                                   const int* __restrict__ pi,
                                                   const int* __restrict__ pj,
                                                   const int* __restrict__ ni,
                                                   const int* __restrict__ nj,
                                                   int P, float* __restrict__ lsig) {
  int wid = blockIdx.x * 4 + (threadIdx.x >> 6);
  int lane = threadIdx.x & 63;
  if (wid >= 2 * P) return;
  bool isneg = wid >= P;
  int p = isneg ? wid - P : wid;
  int i = isneg ? ni[p] : pi[p];
  int j = isneg ? nj[p] : pj[p];
  short8 a = ((const short8*)(ZS1 + (size_t)i * HD))[lane];
  short8 b = ((const short8*)(ZS2 + (size_t)j * HD))[lane];
  float s = 0.f;
#pragma unroll
  for (int t = 0; t < 8; ++t)
    s = fmaf(bf2f((unsigned short)a[t]), bf2f((unsigned short)b[t]), s);
#pragma unroll
  for (int off = 1; off < 64; off <<= 1) s += __shfl_xor(s, off);
  if (lane == 0) {
    float ip = isneg ? -s : s;
    lsig[wid] = fminf(ip, 0.f) - log1pf(expf(-fabsf(ip)));
  }
}

// ---------------- parallel partial reduction -> per-block partials ----------------
#define RED_BLOCKS 128
__global__ __launch_bounds__(256) void reduce_partial(const float* __restrict__ acc,
                                                      const float* __restrict__ lsig,
                                                      int P, float* __restrict__ part) {
  __shared__ float red[6][4];
  int tid = threadIdx.x;
  int gid = blockIdx.x * 256 + tid;
  int stride = gridDim.x * 256;
  float loc[6] = {0.f, 0.f, 0.f, 0.f, 0.f, 0.f};
  for (int idx = gid; idx < 2 * NR; idx += stride) {
    int l = idx >> 12, i = idx & (NR - 1);
    const float* base = acc + (size_t)l * 4 * NR;
    float t0 = logf(base[NR + i] / (base[i] + 1e-8f));              // log(rp/rs)
    float t1 = logf(base[3 * NR + i] / (base[2 * NR + i] + 1e-8f)); // log(cp/cs)
    if (l == 0) { loc[0] += t0; loc[1] += t1; }
    else        { loc[2] += t0; loc[3] += t1; }
  }
  for (int i = gid; i < P; i += stride) loc[4] += lsig[i];
  for (int i = gid; i < P; i += stride) loc[5] += lsig[P + i];
  int wv = tid >> 6, ln = tid & 63;
#pragma unroll
  for (int q = 0; q < 6; ++q) {
    float s = loc[q];
#pragma unroll
    for (int off = 1; off < 64; off <<= 1) s += __shfl_xor(s, off);
    if (ln == 0) red[q][wv] = s;
  }
  __syncthreads();
  if (tid < 6) part[blockIdx.x * 6 + tid] = red[tid][0] + red[tid][1] + red[tid][2] + red[tid][3];
}

// ---------------- combine partials -> scalar (1 wave) ----------------
__global__ __launch_bounds__(64) void finalize2(const float* __restrict__ part,
                                                int P, float* __restrict__ out) {
  int ln = threadIdx.x;  // 0..63
  float t[6];
#pragma unroll
  for (int q = 0; q < 6; ++q) {
    float s = part[ln * 6 + q] + part[(ln + 64) * 6 + q];
#pragma unroll
    for (int off = 1; off < 64; off <<= 1) s += __shfl_xor(s, off);
    t[q] = s;
  }
  if (ln == 0) {
    float loss1 = LAMBDA * (-t[0] / (float)NR) + (1.f - LAMBDA) * (-t[1] / (float)NR);
    float loss2 = LAMBDA * (-t[2] / (float)NR) + (1.f - LAMBDA) * (-t[3] / (float)NR);
    float loss_main = -(t[4] / (float)P) + (t[5] / (float)P);
    out[0] = loss_main + loss1 + loss2;
  }
}

extern "C" void kernel_launch(void* const* d_in, const int* in_sizes, int n_in,
                              void* d_out, int out_size, void* d_ws, size_t ws_size,
                              hipStream_t stream) {
  const float* z_mp1 = (const float*)d_in[0];
  const float* z_sc1 = (const float*)d_in[1];
  const float* pos1 = (const float*)d_in[2];
  const float* z_mp2 = (const float*)d_in[3];
  const float* z_sc2 = (const float*)d_in[4];
  const float* pos2 = (const float*)d_in[5];
  const float* W1 = (const float*)d_in[6];
  const float* b1 = (const float*)d_in[7];
  const float* W2 = (const float*)d_in[8];
  const float* b2 = (const float*)d_in[9];
  const int* pi = (const int*)d_in[10];
  const int* pj = (const int*)d_in[11];
  const int* ni = (const int*)d_in[12];
  const int* nj = (const int*)d_in[13];
  const int P = in_sizes[10];

  char* ws = (char*)d_ws;
  float* ACC = (float*)(ws);                                   // 256KB zeroed: [0,8*4096) acc
  float* PART = ACC + 8 * 4096;                                // 128*6 f32 (fully overwritten)
  float* INV = (float*)(ws + 260 * 1024);                      // 2*4096 f32
  float* LSIG = (float*)(ws + 300 * 1024);                     // 2P f32 (~538KB, ends <1MB)
  unsigned short* W1b = (unsigned short*)(ws + 1024 * 1024);       // 512KB
  unsigned short* W2b = (unsigned short*)(ws + 1536 * 1024);       // 512KB
  unsigned short* ZB0 = (unsigned short*)(ws + 2 * 1024 * 1024);   // 4MB
  unsigned short* ZB1 = (unsigned short*)(ws + 6 * 1024 * 1024);   // 4MB
  unsigned short* ZSB1 = (unsigned short*)(ws + 10 * 1024 * 1024); // 4MB bf16 zsum1
  unsigned short* ZSB2 = (unsigned short*)(ws + 14 * 1024 * 1024); // 4MB bf16 zsum2
  unsigned short* HBm = (unsigned short*)(ws + 10 * 1024 * 1024);  // alias ZSB1 (pair done first)
  unsigned short* HBs = (unsigned short*)(ws + 14 * 1024 * 1024);  // alias ZSB2
  unsigned short* PAb = (unsigned short*)(ws + 18 * 1024 * 1024);  // 4MB
  unsigned short* PBb = (unsigned short*)(ws + 22 * 1024 * 1024);  // 4MB
  unsigned long long* PU1 = (unsigned long long*)(ws + 26 * 1024 * 1024);  // 2MB bitmask
  unsigned long long* PU2 = (unsigned long long*)(ws + 28 * 1024 * 1024);  // 2MB bitmask

  hipMemsetAsync(ACC, 0, 16 * 4096 * sizeof(float), stream);

  prep<<<4608, 256, 0, stream>>>(W1, W2, z_mp1, z_sc1, z_mp2, z_sc2, W1b, W2b, ZSB1, ZSB2);
  pair_logsig<<<(2 * P + 3) / 4, 256, 0, stream>>>(ZSB1, ZSB2, pi, pj, ni, nj, P, LSIG);
  pos_pack2<<<2048, 256, 0, stream>>>(pos1, pos2, PU1, PU2);

  dim3 gP(4, 64);    // proj: N/128 x (2 streams * M/128)
  dim3 gS(32, 32);   // sim: 4096/128 each dim
  for (int ll = 0; ll < 2; ++ll) {
    const float* zm = ll ? z_mp2 : z_mp1;
    const float* zs = ll ? z_sc2 : z_sc1;
    const unsigned int* bm = (const unsigned int*)(ll ? PU2 : PU1);
    cast2_bf16<<<4096, 256, 0, stream>>>(zm, zs, ZB0, ZB1);
    proj_mfma<true><<<gP, 256, 0, stream>>>(ZB0, ZB1, W1b, b1, HBm, HBs);
    proj_mfma<false><<<gP, 256, 0, stream>>>(HBm, HBs, W2b, b2, PAb, PBb);
    rownorm2_bf<<<2048, 256, 0, stream>>>(PAb, PBb, INV);
    sim_mfma<<<gS, 256, 0, stream>>>(PAb, PBb, INV, INV + 4096, bm,
                                     ACC + (size_t)(ll * 4 + 0) * 4096, ACC + (size_t)(ll * 4 + 1) * 4096,
                                     ACC + (size_t)(ll * 4 + 2) * 4096, ACC + (size_t)(ll * 4 + 3) * 4096);
  }
  reduce_partial<<<RED_BLOCKS, 256, 0, stream>>>(ACC, LSIG, P, PART);
  finalize2<<<1, 64, 0, stream>>>(PART, P, (float*)d_out);
}

// Round 14
// 403.914 us; speedup vs baseline: 1.0688x; 1.0015x over previous
//
#include <hip/hip_runtime.h>
#include <math.h>

#define TAU_INV 1.25f
#define LOG2E 1.4426950408889634f
#define LAMBDA 0.5f
#define NR 4096
#define HD 512

typedef __attribute__((ext_vector_type(8))) short short8;
typedef __attribute__((ext_vector_type(4))) float f32x4;
typedef __attribute__((ext_vector_type(4))) unsigned short ushort4v;

#if defined(__has_builtin)
#if __has_builtin(__builtin_amdgcn_exp2f)
#define FEXP2 __builtin_amdgcn_exp2f
#endif
#endif
#ifndef FEXP2
#define FEXP2 exp2f
#endif

static __device__ __forceinline__ unsigned short f2bf(float f) {
  unsigned int u = __float_as_uint(f);
  u += 0x7fff + ((u >> 16) & 1);   // RNE
  return (unsigned short)(u >> 16);
}
static __device__ __forceinline__ float bf2f(unsigned short s) {
  return __uint_as_float(((unsigned int)s) << 16);
}

// ---------------- prep: W1/W2 casts + zsum1/zsum2 (bf16), one launch ----------------
__global__ __launch_bounds__(256) void prep(const float* __restrict__ W1, const float* __restrict__ W2,
                                            const float* __restrict__ zm1, const float* __restrict__ zs1,
                                            const float* __restrict__ zm2, const float* __restrict__ zs2,
                                            unsigned short* __restrict__ W1b, unsigned short* __restrict__ W2b,
                                            unsigned short* __restrict__ ZSB1, unsigned short* __restrict__ ZSB2) {
  int gid = blockIdx.x * 256 + threadIdx.x;
  if (gid < 131072) {
    const float* src = gid < 65536 ? W1 : W2;
    unsigned short* dst = gid < 65536 ? W1b : W2b;
    int i = gid & 65535;
    float4 v = ((const float4*)src)[i];
    ushort4v o;
    o.x = f2bf(v.x); o.y = f2bf(v.y); o.z = f2bf(v.z); o.w = f2bf(v.w);
    ((ushort4v*)dst)[i] = o;
  } else if (gid < 1179648) {
    int g = gid - 131072;
    const float* a = g < 524288 ? zm1 : zm2;
    const float* b = g < 524288 ? zs1 : zs2;
    unsigned short* o = g < 524288 ? ZSB1 : ZSB2;
    int i = g & 524287;
    float4 x = ((const float4*)a)[i], y = ((const float4*)b)[i];
    ushort4v r;
    r.x = f2bf(x.x + y.x); r.y = f2bf(x.y + y.y);
    r.z = f2bf(x.z + y.z); r.w = f2bf(x.w + y.w);
    ((ushort4v*)o)[i] = r;
  }
}

// ---------------- both z casts for one stream: zm->ZB0, zs->ZB1 ----------------
__global__ __launch_bounds__(256) void cast2_bf16(const float* __restrict__ zm,
                                                  const float* __restrict__ zs,
                                                  unsigned short* __restrict__ ZB0,
                                                  unsigned short* __restrict__ ZB1) {
  int gid = blockIdx.x * 256 + threadIdx.x;
  const float* src = gid < 524288 ? zm : zs;
  unsigned short* dst = gid < 524288 ? ZB0 : ZB1;
  int i = gid & 524287;
  float4 v = ((const float4*)src)[i];
  ushort4v o;
  o.x = f2bf(v.x); o.y = f2bf(v.y); o.z = f2bf(v.z); o.w = f2bf(v.w);
  ((ushort4v*)dst)[i] = o;
}

// ---------------- both pos -> bitmasks: 4 independent blocks/iter for load ILP ----------------
// Layout (unchanged): word ww*4+j = nibbles of lanes 16j..16j+15; flat elem W*64+b <-> bit b of word W.
// Grid MUST be 2048 blocks: 8192 waves x 4 blocks x 4 iters covers 2*65536 blocks exactly.
__global__ __launch_bounds__(256) void pos_pack2(const float* __restrict__ pos1,
                                                 const float* __restrict__ pos2,
                                                 unsigned long long* __restrict__ b1,
                                                 unsigned long long* __restrict__ b2) {
  int lane = threadIdx.x & 63;
  int gw = (blockIdx.x * 256 + threadIdx.x) >> 6;   // 0..8191
  const int nblk = NR * NR / 256;                    // 65536 per matrix
  const int wstride = 8192 * 4;                      // blocks consumed per iteration round
  for (int base = gw * 4; base < 2 * nblk; base += wstride) {
    // 4 independent loads up-front (groups of 4 never straddle the matrix boundary)
    const float* pos = base < nblk ? pos1 : pos2;
    unsigned long long* bits = base < nblk ? b1 : b2;
    int bb = base < nblk ? base : base - nblk;
    float4 v0 = ((const float4*)pos)[(size_t)(bb + 0) * 64 + lane];
    float4 v1 = ((const float4*)pos)[(size_t)(bb + 1) * 64 + lane];
    float4 v2 = ((const float4*)pos)[(size_t)(bb + 2) * 64 + lane];
    float4 v3 = ((const float4*)pos)[(size_t)(bb + 3) * 64 + lane];
    unsigned long long val[4];
    int sh = 4 * (lane & 15);
    val[0] = (unsigned long long)((v0.x > 0.5f ? 1u : 0u) | (v0.y > 0.5f ? 2u : 0u) |
                                  (v0.z > 0.5f ? 4u : 0u) | (v0.w > 0.5f ? 8u : 0u)) << sh;
    val[1] = (unsigned long long)((v1.x > 0.5f ? 1u : 0u) | (v1.y > 0.5f ? 2u : 0u) |
                                  (v1.z > 0.5f ? 4u : 0u) | (v1.w > 0.5f ? 8u : 0u)) << sh;
    val[2] = (unsigned long long)((v2.x > 0.5f ? 1u : 0u) | (v2.y > 0.5f ? 2u : 0u) |
                                  (v2.z > 0.5f ? 4u : 0u) | (v2.w > 0.5f ? 8u : 0u)) << sh;
    val[3] = (unsigned long long)((v3.x > 0.5f ? 1u : 0u) | (v3.y > 0.5f ? 2u : 0u) |
                                  (v3.z > 0.5f ? 4u : 0u) | (v3.w > 0.5f ? 8u : 0u)) << sh;
#pragma unroll
    for (int off = 1; off < 16; off <<= 1) {
#pragma unroll
      for (int k = 0; k < 4; ++k) val[k] |= __shfl_xor(val[k], off);
    }
    if ((lane & 15) == 0) {
#pragma unroll
      for (int k = 0; k < 4; ++k)
        bits[(size_t)(bb + k) * 4 + (lane >> 4)] = val[k];
    }
  }
}

// ============ MFMA GEMM core macros (128x128 tile, BK=64, XOR-swizzled LDS) ============
#define GEMM_STAGE(Aptr, Bptr, rb, cb_, kb)                                                     \
  {                                                                                             \
    _Pragma("unroll") for (int q = 0; q < 4; ++q) {                                             \
      int r0 = q * 32 + w * 8;                                                                  \
      const char* sa = (const char*)(Aptr) + ((size_t)((rb) + r0 + lrow) << 10) + (kb)*128 + scb;\
      const char* sb = (const char*)(Bptr) + ((size_t)((cb_) + r0 + lrow) << 10) + (kb)*128 + scb;\
      __builtin_amdgcn_global_load_lds((const __attribute__((address_space(1))) unsigned int*)sa,\
          (__attribute__((address_space(3))) unsigned int*)(void*)((char*)As + r0 * 128), 16, 0, 0);\
      __builtin_amdgcn_global_load_lds((const __attribute__((address_space(1))) unsigned int*)sb,\
          (__attribute__((address_space(3))) unsigned int*)(void*)((char*)Bs + r0 * 128), 16, 0, 0);\
    }                                                                                           \
  }

#define GEMM_COMPUTE()                                                                          \
  {                                                                                             \
    _Pragma("unroll") for (int kk = 0; kk < 2; ++kk) {                                          \
      short8 av[4], bv[4];                                                                      \
      _Pragma("unroll") for (int mf = 0; mf < 4; ++mf) {                                        \
        int row = wr * 64 + mf * 16 + (l & 15);                                                 \
        int kbyte = ((kk * 64) + ((l >> 4) * 16)) ^ ((l & 7) << 4);                             \
        av[mf] = *(const short8*)((const char*)As + row * 128 + kbyte);                         \
      }                                                                                        \
      _Pragma("unroll") for (int nf = 0; nf < 4; ++nf) {                                        \
        int row = wc * 64 + nf * 16 + (l & 15);                                                 \
        int kbyte = ((kk * 64) + ((l >> 4) * 16)) ^ ((l & 7) << 4);                             \
        bv[nf] = *(const short8*)((const char*)Bs + row * 128 + kbyte);                         \
      }                                                                                        \
      _Pragma("unroll") for (int mf = 0; mf < 4; ++mf)                                          \
        _Pragma("unroll") for (int nf = 0; nf < 4; ++nf)                                        \
          acc[mf][nf] = __builtin_amdgcn_mfma_f32_16x16x32_bf16(av[mf], bv[nf], acc[mf][nf], 0, 0, 0);\
    }                                                                                           \
  }

// ---------------- proj GEMM: C = A @ W^T + bias (optional ELU), bf16 in/out, 2 streams ----------------
template <bool DO_ELU>
__global__ __launch_bounds__(256) void proj_mfma(const unsigned short* __restrict__ A0,
                                                 const unsigned short* __restrict__ A1,
                                                 const unsigned short* __restrict__ B,
                                                 const float* __restrict__ bias,
                                                 unsigned short* __restrict__ C0,
                                                 unsigned short* __restrict__ C1) {
  __shared__ unsigned short As[128 * 64];
  __shared__ unsigned short Bs[128 * 64];
  const int tid = threadIdx.x;
  const int l = tid & 63, w = tid >> 6;
  const int wr = w >> 1, wc = w & 1;
  const int stream_id = blockIdx.y >> 5;
  const int rowbase = (blockIdx.y & 31) * 128;
  const int colbase = blockIdx.x * 128;
  const unsigned short* A = stream_id ? A1 : A0;
  unsigned short* C = stream_id ? C1 : C0;
  const int lrow = l >> 3;
  const int scb = ((l & 7) ^ lrow) << 4;

  f32x4 acc[4][4];
#pragma unroll
  for (int i = 0; i < 4; ++i)
#pragma unroll
    for (int j = 0; j < 4; ++j) acc[i][j] = (f32x4){0.f, 0.f, 0.f, 0.f};

  for (int kb = 0; kb < 8; ++kb) {
    GEMM_STAGE(A, B, rowbase, colbase, kb);
    __syncthreads();
    GEMM_COMPUTE();
    __syncthreads();
  }

  const int cq = l >> 4, cn = l & 15;
#pragma unroll
  for (int mf = 0; mf < 4; ++mf) {
#pragma unroll
    for (int nf = 0; nf < 4; ++nf) {
      int col = colbase + wc * 64 + nf * 16 + cn;
      float bb = bias[col];
#pragma unroll
      for (int j = 0; j < 4; ++j) {
        int row = rowbase + wr * 64 + mf * 16 + cq * 4 + j;
        float v = acc[mf][nf][j] + bb;
        if (DO_ELU) v = v > 0.f ? v : expm1f(v);
        C[(size_t)row * HD + col] = f2bf(v);
      }
    }
  }
}

// ---------------- row inv-norms for BOTH projected matrices, one launch ----------------
__global__ __launch_bounds__(256) void rownorm2_bf(const unsigned short* __restrict__ ZA,
                                                   const unsigned short* __restrict__ ZB,
                                                   float* __restrict__ inv) {
  int wid = blockIdx.x * 4 + (threadIdx.x >> 6);   // 0..8191
  int lane = threadIdx.x & 63;
  if (wid >= 2 * NR) return;
  const unsigned short* Z = wid < NR ? ZA : ZB;
  int r = wid < NR ? wid : wid - NR;
  short8 v = ((const short8*)(Z + (size_t)r * HD))[lane];
  float s = 0.f;
#pragma unroll
  for (int j = 0; j < 8; ++j) {
    float f = bf2f((unsigned short)v[j]);
    s += f * f;
  }
#pragma unroll
  for (int off = 1; off < 64; off <<= 1) s += __shfl_xor(s, off);
  if (lane == 0) inv[wid] = 1.f / sqrtf(s);
}

// ---------------- fused similarity (MFMA) + fast-exp + bitmask pos row/col reductions ----------------
__global__ __launch_bounds__(256) void sim_mfma(const unsigned short* __restrict__ PA,
                                                const unsigned short* __restrict__ PB,
                                                const float* __restrict__ invA,
                                                const float* __restrict__ invB,
                                                const unsigned int* __restrict__ BM,  // bitmask, row*128 u32s
                                                float* __restrict__ accRS,
                                                float* __restrict__ accRP,
                                                float* __restrict__ accCS,
                                                float* __restrict__ accCP) {
  __shared__ unsigned short As[128 * 64];
  __shared__ unsigned short Bs[128 * 64];
  const int tid = threadIdx.x;
  const int l = tid & 63, w = tid >> 6;
  const int wr = w >> 1, wc = w & 1;
  const int rowbase = blockIdx.y * 128;
  const int colbase = blockIdx.x * 128;
  const int lrow = l >> 3;
  const int scb = ((l & 7) ^ lrow) << 4;

  f32x4 acc[4][4];
#pragma unroll
  for (int i = 0; i < 4; ++i)
#pragma unroll
    for (int j = 0; j < 4; ++j) acc[i][j] = (f32x4){0.f, 0.f, 0.f, 0.f};

  for (int kb = 0; kb < 8; ++kb) {
    GEMM_STAGE(PA, PB, rowbase, colbase, kb);
    __syncthreads();
    GEMM_COMPUTE();
    __syncthreads();
  }

  const int cq = l >> 4, cn = l & 15;
  // scales: fold tau^-1 * log2(e) into row scale; m = 2^(dot*srA*scB)
  float sr[4][4], sc[4];
#pragma unroll
  for (int mf = 0; mf < 4; ++mf) {
    float4 iv = *(const float4*)(invA + rowbase + wr * 64 + mf * 16 + cq * 4);
    sr[mf][0] = iv.x * (TAU_INV * LOG2E); sr[mf][1] = iv.y * (TAU_INV * LOG2E);
    sr[mf][2] = iv.z * (TAU_INV * LOG2E); sr[mf][3] = iv.w * (TAU_INV * LOG2E);
  }
#pragma unroll
  for (int nf = 0; nf < 4; ++nf) sc[nf] = invB[colbase + wc * 64 + nf * 16 + cn];

#pragma unroll
  for (int mf = 0; mf < 4; ++mf)
#pragma unroll
    for (int nf = 0; nf < 4; ++nf)
#pragma unroll
      for (int j = 0; j < 4; ++j)
        acc[mf][nf][j] = FEXP2(acc[mf][nf][j] * sr[mf][j] * sc[nf]);

  // row sums + pos-weighted row sums (pos bits from BM[row][col])
#pragma unroll
  for (int mf = 0; mf < 4; ++mf) {
    float rs[4] = {0.f, 0.f, 0.f, 0.f}, rp[4] = {0.f, 0.f, 0.f, 0.f};
#pragma unroll
    for (int j = 0; j < 4; ++j) {
      int row = rowbase + wr * 64 + mf * 16 + cq * 4 + j;
      const unsigned int* bmr = BM + (size_t)row * 128 + (colbase >> 5) + wc * 2;
      unsigned int w0 = bmr[0], w1 = bmr[1];   // cols [base,base+32), [base+32,base+64)
#pragma unroll
      for (int nf = 0; nf < 4; ++nf) {
        float m = acc[mf][nf][j];
        rs[j] += m;
        unsigned int wsel = (nf < 2) ? w0 : w1;
        if ((wsel >> ((nf * 16 + cn) & 31)) & 1) rp[j] += m;
      }
    }
#pragma unroll
    for (int off = 1; off < 16; off <<= 1) {
#pragma unroll
      for (int j = 0; j < 4; ++j) { rs[j] += __shfl_xor(rs[j], off); rp[j] += __shfl_xor(rp[j], off); }
    }
    if (cn == 0) {
#pragma unroll
      for (int j = 0; j < 4; ++j) {
        int row = rowbase + wr * 64 + mf * 16 + cq * 4 + j;
        atomicAdd(&accRS[row], rs[j]);
        atomicAdd(&accRP[row], rp[j]);
      }
    }
  }

  // col sums + pos^T-weighted col sums (pos bits from BM[col][row])
  float cs[4] = {0.f, 0.f, 0.f, 0.f}, cp[4] = {0.f, 0.f, 0.f, 0.f};
#pragma unroll
  for (int nf = 0; nf < 4; ++nf) {
    int col = colbase + wc * 64 + nf * 16 + cn;
    const unsigned int* bmc = BM + (size_t)col * 128 + (rowbase >> 5) + wr * 2;
    unsigned int w0 = bmc[0], w1 = bmc[1];     // rows [base,base+32), [base+32,base+64)
#pragma unroll
    for (int mf = 0; mf < 4; ++mf) {
      unsigned int wsel = (mf < 2) ? w0 : w1;
#pragma unroll
      for (int j = 0; j < 4; ++j) {
        float m = acc[mf][nf][j];
        cs[nf] += m;
        if ((wsel >> ((mf * 16 + cq * 4 + j) & 31)) & 1) cp[nf] += m;
      }
    }
  }
#pragma unroll
  for (int off = 16; off < 64; off <<= 1) {
#pragma unroll
    for (int nf = 0; nf < 4; ++nf) { cs[nf] += __shfl_xor(cs[nf], off); cp[nf] += __shfl_xor(cp[nf], off); }
  }
  if (cq == 0) {
#pragma unroll
    for (int nf = 0; nf < 4; ++nf) {
      int col = colbase + wc * 64 + nf * 16 + cn;
      atomicAdd(&accCS[col], cs[nf]);
      atomicAdd(&accCP[col], cp[nf]);
    }
  }
}

// ---------------- pair dot + log-sigmoid (bf16 zsum gathers) ----------------
__global__ __launch_bounds__(256) void pair_logsig(const unsigned short* __restrict__ ZS1,
                                                   const unsigned short* __restrict__ ZS2,
                                                   const int* __restrict__ pi,
                                                   const int* __restrict__ pj,
                                                   const int* __restrict__ ni,
                                                   const int* __restrict__ nj,
                                                   int P, float* __restrict__ lsig) {
  int wid = blockIdx.x * 4 + (threadIdx.x >> 6);
  int lane = threadIdx.x & 63;
  if (wid >= 2 * P) return;
  bool isneg = wid >= P;
  int p = isneg ? wid - P : wid;
  int i = isneg ? ni[p] : pi[p];
  int j = isneg ? nj[p] : pj[p];
  short8 a = ((const short8*)(ZS1 + (size_t)i * HD))[lane];
  short8 b = ((const short8*)(ZS2 + (size_t)j * HD))[lane];
  float s = 0.f;
#pragma unroll
  for (int t = 0; t < 8; ++t)
    s = fmaf(bf2f((unsigned short)a[t]), bf2f((unsigned short)b[t]), s);
#pragma unroll
  for (int off = 1; off < 64; off <<= 1) s += __shfl_xor(s, off);
  if (lane == 0) {
    float ip = isneg ? -s : s;
    lsig[wid] = fminf(ip, 0.f) - log1pf(expf(-fabsf(ip)));
  }
}

// ---------------- parallel partial reduction -> per-block partials ----------------
#define RED_BLOCKS 128
__global__ __launch_bounds__(256) void reduce_partial(const float* __restrict__ acc,
                                                      const float* __restrict__ lsig,
                                                      int P, float* __restrict__ part) {
  __shared__ float red[6][4];
  int tid = threadIdx.x;
  int gid = blockIdx.x * 256 + tid;
  int stride = gridDim.x * 256;
  float loc[6] = {0.f, 0.f, 0.f, 0.f, 0.f, 0.f};
  for (int idx = gid; idx < 2 * NR; idx += stride) {
    int l = idx >> 12, i = idx & (NR - 1);
    const float* base = acc + (size_t)l * 4 * NR;
    float t0 = logf(base[NR + i] / (base[i] + 1e-8f));              // log(rp/rs)
    float t1 = logf(base[3 * NR + i] / (base[2 * NR + i] + 1e-8f)); // log(cp/cs)
    if (l == 0) { loc[0] += t0; loc[1] += t1; }
    else        { loc[2] += t0; loc[3] += t1; }
  }
  for (int i = gid; i < P; i += stride) loc[4] += lsig[i];
  for (int i = gid; i < P; i += stride) loc[5] += lsig[P + i];
  int wv = tid >> 6, ln = tid & 63;
#pragma unroll
  for (int q = 0; q < 6; ++q) {
    float s = loc[q];
#pragma unroll
    for (int off = 1; off < 64; off <<= 1) s += __shfl_xor(s, off);
    if (ln == 0) red[q][wv] = s;
  }
  __syncthreads();
  if (tid < 6) part[blockIdx.x * 6 + tid] = red[tid][0] + red[tid][1] + red[tid][2] + red[tid][3];
}

// ---------------- combine partials -> scalar (1 wave) ----------------
__global__ __launch_bounds__(64) void finalize2(const float* __restrict__ part,
                                                int P, float* __restrict__ out) {
  int ln = threadIdx.x;  // 0..63
  float t[6];
#pragma unroll
  for (int q = 0; q < 6; ++q) {
    float s = part[ln * 6 + q] + part[(ln + 64) * 6 + q];
#pragma unroll
    for (int off = 1; off < 64; off <<= 1) s += __shfl_xor(s, off);
    t[q] = s;
  }
  if (ln == 0) {
    float loss1 = LAMBDA * (-t[0] / (float)NR) + (1.f - LAMBDA) * (-t[1] / (float)NR);
    float loss2 = LAMBDA * (-t[2] / (float)NR) + (1.f - LAMBDA) * (-t[3] / (float)NR);
    float loss_main = -(t[4] / (float)P) + (t[5] / (float)P);
    out[0] = loss_main + loss1 + loss2;
  }
}

extern "C" void kernel_launch(void* const* d_in, const int* in_sizes, int n_in,
                              void* d_out, int out_size, void* d_ws, size_t ws_size,
                              hipStream_t stream) {
  const float* z_mp1 = (const float*)d_in[0];
  const float* z_sc1 = (const float*)d_in[1];
  const float* pos1 = (const float*)d_in[2];
  const float* z_mp2 = (const float*)d_in[3];
  const float* z_sc2 = (const float*)d_in[4];
  const float* pos2 = (const float*)d_in[5];
  const float* W1 = (const float*)d_in[6];
  const float* b1 = (const float*)d_in[7];
  const float* W2 = (const float*)d_in[8];
  const float* b2 = (const float*)d_in[9];
  const int* pi = (const int*)d_in[10];
  const int* pj = (const int*)d_in[11];
  const int* ni = (const int*)d_in[12];
  const int* nj = (const int*)d_in[13];
  const int P = in_sizes[10];

  char* ws = (char*)d_ws;
  float* ACC = (float*)(ws);                                   // 256KB zeroed: [0,8*4096) acc
  float* PART = ACC + 8 * 4096;                                // 128*6 f32 (fully overwritten)
  float* INV = (float*)(ws + 260 * 1024);                      // 2*4096 f32
  float* LSIG = (float*)(ws + 300 * 1024);                     // 2P f32 (~538KB, ends <1MB)
  unsigned short* W1b = (unsigned short*)(ws + 1024 * 1024);       // 512KB
  unsigned short* W2b = (unsigned short*)(ws + 1536 * 1024);       // 512KB
  unsigned short* ZB0 = (unsigned short*)(ws + 2 * 1024 * 1024);   // 4MB
  unsigned short* ZB1 = (unsigned short*)(ws + 6 * 1024 * 1024);   // 4MB
  unsigned short* ZSB1 = (unsigned short*)(ws + 10 * 1024 * 1024); // 4MB bf16 zsum1
  unsigned short* ZSB2 = (unsigned short*)(ws + 14 * 1024 * 1024); // 4MB bf16 zsum2
  unsigned short* HBm = (unsigned short*)(ws + 10 * 1024 * 1024);  // alias ZSB1 (pair done first)
  unsigned short* HBs = (unsigned short*)(ws + 14 * 1024 * 1024);  // alias ZSB2
  unsigned short* PAb = (unsigned short*)(ws + 18 * 1024 * 1024);  // 4MB
  unsigned short* PBb = (unsigned short*)(ws + 22 * 1024 * 1024);  // 4MB
  unsigned long long* PU1 = (unsigned long long*)(ws + 26 * 1024 * 1024);  // 2MB bitmask
  unsigned long long* PU2 = (unsigned long long*)(ws + 28 * 1024 * 1024);  // 2MB bitmask

  hipMemsetAsync(ACC, 0, 16 * 4096 * sizeof(float), stream);

  prep<<<4608, 256, 0, stream>>>(W1, W2, z_mp1, z_sc1, z_mp2, z_sc2, W1b, W2b, ZSB1, ZSB2);
  pair_logsig<<<(2 * P + 3) / 4, 256, 0, stream>>>(ZSB1, ZSB2, pi, pj, ni, nj, P, LSIG);
  pos_pack2<<<2048, 256, 0, stream>>>(pos1, pos2, PU1, PU2);

  dim3 gP(4, 64);    // proj: N/128 x (2 streams * M/128)
  dim3 gS(32, 32);   // sim: 4096/128 each dim
  for (int ll = 0; ll < 2; ++ll) {
    const float* zm = ll ? z_mp2 : z_mp1;
    const float* zs = ll ? z_sc2 : z_sc1;
    const unsigned int* bm = (const unsigned int*)(ll ? PU2 : PU1);
    cast2_bf16<<<4096, 256, 0, stream>>>(zm, zs, ZB0, ZB1);
    proj_mfma<true><<<gP, 256, 0, stream>>>(ZB0, ZB1, W1b, b1, HBm, HBs);
    proj_mfma<false><<<gP, 256, 0, stream>>>(HBm, HBs, W2b, b2, PAb, PBb);
    rownorm2_bf<<<2048, 256, 0, stream>>>(PAb, PBb, INV);
    sim_mfma<<<gS, 256, 0, stream>>>(PAb, PBb, INV, INV + 4096, bm,
                                     ACC + (size_t)(ll * 4 + 0) * 4096, ACC + (size_t)(ll * 4 + 1) * 4096,
                                     ACC + (size_t)(ll * 4 + 2) * 4096, ACC + (size_t)(ll * 4 + 3) * 4096);
  }
  reduce_partial<<<RED_BLOCKS, 256, 0, stream>>>(ACC, LSIG, P, PART);
  finalize2<<<1, 64, 0, stream>>>(PART, P, (float*)d_out);
}